// Round 1
// baseline (64.459 us; speedup 1.0000x reference)
//
#include <hip/hip_runtime.h>

// Problem constants (from reference setup_inputs):
//   B=128 batch, L=4096 doc length, O=10 options, W=5 words/option
// out[b][o] = (sum_w sum_l prob[b][l] * (opt[b][o][w]==idx[b][l])) / #nonzero-words
#define BB 128
#define LL 4096
#define OO 10
#define WW 5

__global__ __launch_bounds__(256) void OptionAttentionSum_kernel(
    const int* __restrict__ doc_idx,     // (B, L) int32
    const float* __restrict__ doc_prob,  // (B, L) f32
    const int* __restrict__ options,     // (B, O, W) int32
    float* __restrict__ out)             // (B, O) f32
{
    const int bo = blockIdx.x;        // 0 .. B*O-1
    const int b = bo / OO;
    const int t = threadIdx.x;

    // Block-uniform option words -> scalar loads / broadcast
    const int* opt = options + bo * WW;
    const int w0 = opt[0], w1 = opt[1], w2 = opt[2], w3 = opt[3], w4 = opt[4];

    const int4*   idx4 = (const int4*)(doc_idx + (long)b * LL);
    const float4* p4   = (const float4*)(doc_prob + (long)b * LL);

    float acc = 0.0f;
    // L/4 = 1024 vec4 elements; 256 threads -> 4 iterations, coalesced 16B/lane
#pragma unroll
    for (int it = 0; it < 4; ++it) {
        const int i = it * 256 + t;
        const int4   d = idx4[i];
        const float4 p = p4[i];
        acc += p.x * (float)((d.x == w0) + (d.x == w1) + (d.x == w2) + (d.x == w3) + (d.x == w4));
        acc += p.y * (float)((d.y == w0) + (d.y == w1) + (d.y == w2) + (d.y == w3) + (d.y == w4));
        acc += p.z * (float)((d.z == w0) + (d.z == w1) + (d.z == w2) + (d.z == w3) + (d.z == w4));
        acc += p.w * (float)((d.w == w0) + (d.w == w1) + (d.w == w2) + (d.w == w3) + (d.w == w4));
    }

    // Wave-64 shuffle reduction
#pragma unroll
    for (int off = 32; off > 0; off >>= 1)
        acc += __shfl_down(acc, off, 64);

    __shared__ float warp_sums[4];
    const int wave = t >> 6;
    const int lane = t & 63;
    if (lane == 0) warp_sums[wave] = acc;
    __syncthreads();

    if (t == 0) {
        const float total = warp_sums[0] + warp_sums[1] + warp_sums[2] + warp_sums[3];
        const float divisor = (float)((w0 != 0) + (w1 != 0) + (w2 != 0) + (w3 != 0) + (w4 != 0));
        out[bo] = total / divisor;
    }
}

extern "C" void kernel_launch(void* const* d_in, const int* in_sizes, int n_in,
                              void* d_out, int out_size, void* d_ws, size_t ws_size,
                              hipStream_t stream) {
    const int*   doc_idx  = (const int*)d_in[0];
    const float* doc_prob = (const float*)d_in[1];
    const int*   options  = (const int*)d_in[2];
    float*       out      = (float*)d_out;

    OptionAttentionSum_kernel<<<BB * OO, 256, 0, stream>>>(doc_idx, doc_prob, options, out);
}

// Round 2
// 58.967 us; speedup vs baseline: 1.0931x; 1.0931x over previous
//
#include <hip/hip_runtime.h>

// Problem constants (from reference setup_inputs):
//   B=128 batch, L=4096 doc length, O=10 options, W=5 words/option
// out[b][o] = (sum_w sum_l prob[b][l] * (opt[b][o][w]==idx[b][l])) / #nonzero-words
#define BB 128
#define LL 4096
#define OO 10
#define WW 5

__global__ __launch_bounds__(256) void OptionAttentionSum_kernel(
    const int* __restrict__ doc_idx,     // (B, L) int32
    const float* __restrict__ doc_prob,  // (B, L) f32
    const int* __restrict__ options,     // (B, O, W) int32
    float* __restrict__ out)             // (B, O) f32
{
    // XCD-locality swizzle: blocks sharing batch row b must land on the same
    // XCD (blockIdx % 8 selects XCD). b = blockIdx % 128 keeps all 10 option
    // blocks of a row at the same (mod 8) slot -> doc row served from that
    // XCD's L2 after the first fetch (512 KB/XCD resident vs 4 MB L2).
    const int b = blockIdx.x & (BB - 1);     // BB=128, power of 2
    const int o = blockIdx.x >> 7;           // /128
    const int bo = b * OO + o;
    const int t = threadIdx.x;

    // Block-uniform option words -> scalar loads / broadcast
    const int* opt = options + bo * WW;
    const int w0 = opt[0], w1 = opt[1], w2 = opt[2], w3 = opt[3], w4 = opt[4];

    const int4*   idx4 = (const int4*)(doc_idx + (long)b * LL);
    const float4* p4   = (const float4*)(doc_prob + (long)b * LL);

    float acc = 0.0f;
    // L/4 = 1024 vec4 elements; 256 threads -> 4 iterations, coalesced 16B/lane
#pragma unroll
    for (int it = 0; it < 4; ++it) {
        const int i = it * 256 + t;
        const int4   d = idx4[i];
        const float4 p = p4[i];
        acc += p.x * (float)((d.x == w0) + (d.x == w1) + (d.x == w2) + (d.x == w3) + (d.x == w4));
        acc += p.y * (float)((d.y == w0) + (d.y == w1) + (d.y == w2) + (d.y == w3) + (d.y == w4));
        acc += p.z * (float)((d.z == w0) + (d.z == w1) + (d.z == w2) + (d.z == w3) + (d.z == w4));
        acc += p.w * (float)((d.w == w0) + (d.w == w1) + (d.w == w2) + (d.w == w3) + (d.w == w4));
    }

    // Wave-64 shuffle reduction
#pragma unroll
    for (int off = 32; off > 0; off >>= 1)
        acc += __shfl_down(acc, off, 64);

    __shared__ float warp_sums[4];
    const int wave = t >> 6;
    const int lane = t & 63;
    if (lane == 0) warp_sums[wave] = acc;
    __syncthreads();

    if (t == 0) {
        const float total = warp_sums[0] + warp_sums[1] + warp_sums[2] + warp_sums[3];
        const float divisor = (float)((w0 != 0) + (w1 != 0) + (w2 != 0) + (w3 != 0) + (w4 != 0));
        out[bo] = total / divisor;
    }
}

extern "C" void kernel_launch(void* const* d_in, const int* in_sizes, int n_in,
                              void* d_out, int out_size, void* d_ws, size_t ws_size,
                              hipStream_t stream) {
    const int*   doc_idx  = (const int*)d_in[0];
    const float* doc_prob = (const float*)d_in[1];
    const int*   options  = (const int*)d_in[2];
    float*       out      = (float*)d_out;

    OptionAttentionSum_kernel<<<BB * OO, 256, 0, stream>>>(doc_idx, doc_prob, options, out);
}